// Round 7
// baseline (549.826 us; speedup 1.0000x reference)
//
#include <hip/hip_runtime.h>
#include <math.h>

// STHM layer. B=4, TS=64, SEG=128, D=256, H=8, dh=32, DFF=1024.
// Plain-bf16 MFMA GEMMs (BK=64, XOR-swizzled LDS) + single-barrier MFMA attention.
// Residual streams fp32. Tiny cs-projections K-parallel.
// R3: swapped-QK^T sparsemax (lane-local rows, 2-level shfl Michelot). CONFIRMED.
// R4: bm-major grid (FETCH 66->26 MB) + LDS-staged bf16 C-write (WRITE 129->65=ideal).
//     CONFIRMED, -62 us.
// R5: fusions: t9->t8 (TRS=1), t20->t19 (TRS=2, direct d_out), t14+t16 -> K=512
//     ASPLIT GEMM. CONFIRMED, -28 us.
// R6: tanh-form GELU replacing OCML erff (fc1 epilogue was VALU-bound: 54% VALU
//     vs 13% MFMA). R6 bench was an infra container failure (same signature as
//     R1/R2 which resubmitted clean); R7 resubmits with the sigmoid expressed
//     via __expf + plain division (no nonstandard builtins).

typedef unsigned short u16;
typedef unsigned int u32;
typedef __attribute__((ext_vector_type(8))) short s8v;   // 8 bf16 (4 VGPRs) MFMA frag
typedef __attribute__((ext_vector_type(4))) float f4v;   // MFMA accumulator

#define MFMA16 __builtin_amdgcn_mfma_f32_16x16x32_bf16

#define ASYNC16(lds, g) __builtin_amdgcn_global_load_lds( \
    (const __attribute__((address_space(1))) unsigned int*)(const void*)(g), \
    (__attribute__((address_space(3))) unsigned int*)(void*)(lds), 16, 0, 0)

__device__ __forceinline__ float gelu_fast(float x) {
    // tanh-form GELU: 0.5x(1+tanh(u)) = x*sigmoid(2u), u = 0.79788456(x+0.044715x^3)
    const float x2 = x * x;
    const float u2 = x * fmaf(0.0713548162f, x2, 1.5957691216f);   // 2u
    const float e = __expf(-u2);                                    // v_exp path
    return x / (1.0f + e);                                          // x*sigmoid(2u)
}
__device__ __forceinline__ u16 bf16_rne(float f) {
    u32 u = __float_as_uint(f);
    return (u16)((u + 0x7FFFu + ((u >> 16) & 1u)) >> 16);
}
__device__ __forceinline__ float bf16_to_f(u16 h) {
    return __uint_as_float((u32)h << 16);
}

// ---- Batched weight prep: W(K,N fp32) -> Wh (N,K bf16, transposed), 14 mats ----
// LD = destination row stride (u16); lets two mats interleave K-blocks of one row.
struct WB {
    const float* src[14];
    u16* dst[14];
    int K[14], N[14], LD[14];
};
__global__ __launch_bounds__(256)
void wconv_batch(WB wb)
{
    __shared__ float tile[32][33];
    const int mi = blockIdx.y;
    const int K = wb.K[mi], N = wb.N[mi], LD = wb.LD[mi];
    const int tilesN = N >> 5;
    if ((int)blockIdx.x >= tilesN * (K >> 5)) return;
    const int n0 = (blockIdx.x % tilesN) * 32, k0 = (blockIdx.x / tilesN) * 32;
    const float* W = wb.src[mi];
    u16* Wh = wb.dst[mi];
    const int t = threadIdx.x;
    const int r = t >> 3, c = (t & 7) << 2;
    const float4 f = *(const float4*)&W[(size_t)(k0 + r) * N + n0 + c];
    tile[r][c] = f.x; tile[r][c + 1] = f.y; tile[r][c + 2] = f.z; tile[r][c + 3] = f.w;
    __syncthreads();
    u32 hp[2];
    #pragma unroll
    for (int p = 0; p < 2; ++p) {
        const u16 h0 = bf16_rne(tile[c + p * 2][r]);
        const u16 h1 = bf16_rne(tile[c + p * 2 + 1][r]);
        hp[p] = (u32)h0 | ((u32)h1 << 16);
    }
    uint2 hv; hv.x = hp[0]; hv.y = hp[1];
    *(uint2*)&Wh[(size_t)(n0 + r) * LD + k0 + c] = hv;
}

// ---- fp32 -> bf16 plane (8 elems/thread) ----
__global__ __launch_bounds__(256)
void conv_hi(const float* __restrict__ x, u16* __restrict__ xh)
{
    const size_t base = ((size_t)blockIdx.x * 256 + threadIdx.x) * 8;
    const float4 a = *(const float4*)(x + base);
    const float4 b = *(const float4*)(x + base + 4);
    const float fs[8] = {a.x, a.y, a.z, a.w, b.x, b.y, b.z, b.w};
    __align__(16) u16 hh[8];
    #pragma unroll
    for (int i = 0; i < 8; ++i) hh[i] = bf16_rne(fs[i]);
    *(uint4*)(xh + base) = *(const uint4*)hh;
}

// ---- bias concat + sum ----
__global__ __launch_bounds__(256)
void bias_concat(const float* a0, const float* a1, float* o1,
                 const float* b0, const float* b1, const float* b2, float* o2,
                 const float* c0, const float* c1, float* o3)
{
    const int t = threadIdx.x;
    o1[t] = a0[t]; o1[256 + t] = a1[t];
    o2[t] = b0[t]; o2[256 + t] = b1[t]; o2[512 + t] = b2[t];
    o3[t] = c0[t] + c1[t];
}

// ---- bf16 MFMA GEMM, BK=64, XOR-swizzled LDS rows (row stride 64 u16) ----
// chunk-of-16B at (row, c) stored at chunk position c ^ (row & 7).
// Grid: (bm, bn) bm-major so same-bm blocks share an XCD L2 (A reuse).
// OUTMODE: 0 bf16 plane, 1 bf16+fp32, 2 fp32 only (bf16 staged via LDS->uint4).
// TRS: 0 none; 1 out-row = b*8192 + (r&127)*64 + ((r>>7)&63)   [(b,64,128)->(b,128,64)]
//      2 out-row = b*8192 + (r&63)*128 + ((r>>6)&127)          [(b,128,64)->(b,64,128)]
// ASPLIT: A for k0<256, A2 for k0>=256 (fused two-source K=512 GEMM).
template<int GELU, int RES, int OUTMODE, int TRS, int ASPLIT>
__global__ __launch_bounds__(256)
void gemm_bf16(const u16* __restrict__ A, int lda, const u16* __restrict__ W,
               const float* __restrict__ bias, const float* __restrict__ Rf,
               u16* __restrict__ Cb, float* __restrict__ Cf,
               int M, int N, int K, const u16* __restrict__ A2)
{
    __shared__ __align__(16) u16 SM[128 * 136];    // As | Ws, re-used as C staging
    u16* const As = SM;
    u16* const Ws = SM + 128 * 64;
    const int t = threadIdx.x;
    const int bm = blockIdx.x, bn = blockIdx.y;
    const int w = t >> 6, lane = t & 63;
    const int wy = w >> 1, wx = w & 1;
    const int lm = lane & 15, quad = lane >> 4, kq = quad << 3;
    const int srow = lane >> 3;                        // 0..7
    const int scol = (((lane & 7) ^ srow) << 3);       // swizzled source chunk (u16)
    const size_t arow = (size_t)(bm * 128 + w * 32 + srow) * lda + scol;
    const u16* gW = W + (size_t)(bn * 128 + w * 32 + srow) * K + scol;
    f4v acc[4][4] = {};   // [ic: out-col tile][jr: act-row tile]
    for (int k0 = 0; k0 < K; k0 += 64) {
        const u16* gAk = (ASPLIT && k0 >= 256) ? (A2 + arow + (k0 - 256))
                                               : (A + arow + k0);
        #pragma unroll
        for (int r8 = 0; r8 < 4; ++r8) {
            ASYNC16(&As[(w * 32 + r8 * 8) * 64], gAk + (size_t)(r8 * 8) * lda);
            ASYNC16(&Ws[(w * 32 + r8 * 8) * 64], gW + k0 + (size_t)(r8 * 8) * K);
        }
        __syncthreads();
        #pragma unroll
        for (int ks = 0; ks < 2; ++ks) {
            const int ch = ks * 4 + quad;              // 16B chunk index 0..7
            const int sw = ((ch ^ (lm & 7)) << 3);     // swizzled read offset (u16)
            s8v fw[4], fa[4];
            #pragma unroll
            for (int i = 0; i < 4; ++i) {
                fw[i] = *(const s8v*)&Ws[(wx * 64 + i * 16 + lm) * 64 + sw];
                fa[i] = *(const s8v*)&As[(wy * 64 + i * 16 + lm) * 64 + sw];
            }
            #pragma unroll
            for (int ic = 0; ic < 4; ++ic)
                #pragma unroll
                for (int jr = 0; jr < 4; ++jr)
                    acc[ic][jr] = MFMA16(fw[ic], fa[jr], acc[ic][jr], 0, 0, 0);
        }
        __syncthreads();
    }
    #pragma unroll
    for (int ic = 0; ic < 4; ++ic) {
        const int cloc = wx * 64 + ic * 16 + (quad << 2);
        const int col0 = bn * 128 + cloc;
        const float4 bv = *(const float4*)&bias[col0];
        #pragma unroll
        for (int jr = 0; jr < 4; ++jr) {
            const int rloc = wy * 64 + jr * 16 + lm;
            const int row = bm * 128 + rloc;
            const size_t o = (size_t)row * N + col0;
            float v[4] = {acc[ic][jr][0] + bv.x, acc[ic][jr][1] + bv.y,
                          acc[ic][jr][2] + bv.z, acc[ic][jr][3] + bv.w};
            if (RES) {
                const float4 rv = *(const float4*)(Rf + o);
                v[0] += rv.x; v[1] += rv.y; v[2] += rv.z; v[3] += rv.w;
            }
            if (GELU) {
                #pragma unroll
                for (int r = 0; r < 4; ++r) v[r] = gelu_fast(v[r]);
            }
            if (OUTMODE != 2) {
                uint2 hp;
                hp.x = (u32)bf16_rne(v[0]) | ((u32)bf16_rne(v[1]) << 16);
                hp.y = (u32)bf16_rne(v[2]) | ((u32)bf16_rne(v[3]) << 16);
                *(uint2*)&SM[rloc * 136 + cloc] = hp;   // stage for coalesced write
            }
            if (OUTMODE >= 1) {
                int prow = row;
                if (TRS == 1) prow = ((row >> 13) << 13) + ((row & 127) << 6) + ((row >> 7) & 63);
                if (TRS == 2) prow = ((row >> 13) << 13) + ((row & 63) << 7) + ((row >> 6) & 127);
                float4 fv; fv.x = v[0]; fv.y = v[1]; fv.z = v[2]; fv.w = v[3];
                *(float4*)(Cf + (size_t)prow * N + col0) = fv;
            }
        }
    }
    if (OUTMODE != 2) {   // coalesced bf16 tile write: full 256B rows (TRS permutes rows)
        __syncthreads();
        #pragma unroll
        for (int p = 0; p < 8; ++p) {
            const int idx = p * 256 + t;
            const int rloc = idx >> 4, ch = (idx & 15) << 3;
            const int row = bm * 128 + rloc;
            int prow = row;
            if (TRS == 1) prow = ((row >> 13) << 13) + ((row & 127) << 6) + ((row >> 7) & 63);
            if (TRS == 2) prow = ((row >> 13) << 13) + ((row & 63) << 7) + ((row >> 6) & 127);
            *(uint4*)&Cb[(size_t)prow * N + bn * 128 + ch] =
                *(const uint4*)&SM[rloc * 136 + ch];
        }
    }
}

// ---- K-parallel tiny GEMM: C(10,N) = A(10,K) @ W(K,N) + bias ----
__global__ __launch_bounds__(256)
void gemm_tiny(const float* __restrict__ A, const float* __restrict__ W,
               const float* __restrict__ bias, float* __restrict__ Cf,
               u16* __restrict__ Ch, int K, int N)
{
    __shared__ float red[8][33];
    const int m = blockIdx.x;
    const int ncol = blockIdx.y * 32 + (threadIdx.x & 31);
    const int ks = threadIdx.x >> 5;
    const int kc = K >> 3;
    float p = 0.f;
    for (int k = ks * kc; k < (ks + 1) * kc; ++k)
        p = fmaf(A[(size_t)m * K + k], W[(size_t)k * N + ncol], p);
    red[ks][threadIdx.x & 31] = p;
    __syncthreads();
    if (ks == 0) {
        float s = bias[ncol];
        #pragma unroll
        for (int i = 0; i < 8; ++i) s += red[i][threadIdx.x & 31];
        Cf[(size_t)m * N + ncol] = s;
        if (Ch) Ch[(size_t)m * N + ncol] = bf16_rne(s);
    }
}

// ---- cs V^T builder: v2f (10,256) fp32 -> VT2 (8,32,32) bf16, j>=10 zero ----
__global__ __launch_bounds__(256)
void cs_vt(const float* __restrict__ v2f, u16* __restrict__ VT2)
{
    const int c = threadIdx.x;   // col = h*32+e
    for (int j = 0; j < 32; ++j)
        VT2[c * 32 + j] = (j < 10) ? bf16_rne(v2f[(size_t)j * 256 + c]) : (u16)0;
}

// ---- V (M,256) bf16 -> VT (nb,8,32,S) bf16; block per (nb_idx, h) ----
template<int S>
__global__ __launch_bounds__(256)
void transpose_vt(const u16* __restrict__ V, u16* __restrict__ VT)
{
    __shared__ __align__(16) u16 Vs[S * 40];
    const int t = threadIdx.x;
    const int nb = blockIdx.x >> 3, h = blockIdx.x & 7;
    for (int idx = t; idx < S * 4; idx += 256) {
        const int row = idx >> 2, ch = idx & 3;
        *(uint4*)&Vs[row * 40 + ch * 8] =
            *(const uint4*)&V[((size_t)nb * S + row) * 256 + h * 32 + ch * 8];
    }
    __syncthreads();
    for (int idx = t; idx < 32 * S / 8; idx += 256) {
        const int e = idx / (S / 8), seg = idx % (S / 8);
        const int j0 = seg * 8;
        __align__(16) u16 tmp[8];
        #pragma unroll
        for (int i = 0; i < 8; ++i) tmp[i] = Vs[(j0 + i) * 40 + e];
        *(uint4*)&VT[(((size_t)nb * 8 + h) * 32 + e) * S + j0] = *(const uint4*)tmp;
    }
}

// ---- bf16 MFMA attention: swapped QK^T -> Michelot sparsemax (regs) -> P@V^T ----
template<int L, int S, int SHARED>
__global__ __launch_bounds__(256)
void attn_bf16(const u16* __restrict__ q, int ldq, int qcol0,
               const u16* __restrict__ k, int ldk, int kcol0,
               const u16* __restrict__ VT, u16* __restrict__ ho)
{
    constexpr int S16 = (S + 15) & ~15;
    constexpr int S32 = (S + 31) & ~31;
    constexpr int NT = S16 / 16;
    constexpr int KC = S32 / 32;
    constexpr int LC = L / 64;
    constexpr int SP = S32 + 8;
    __shared__ __align__(16) u16 Qs[64 * 32];
    __shared__ __align__(16) u16 Ks[S16 * 32];
    __shared__ __align__(16) u16 Vs[32 * SP];
    __shared__ __align__(16) u16 Ps[64 * SP];
    const int t = threadIdx.x;
    const int lc = (LC == 1) ? 0 : (blockIdx.x & (LC - 1));
    const int bh = (LC == 1) ? blockIdx.x : (blockIdx.x >> 1);
    const int b = bh >> 3, h = bh & 7;
    const int qrow0 = lc * 64;
    const int w = t >> 6, lane = t & 63;
    const int lm = lane & 15, quad = lane >> 4, kq = quad << 3;

    {
        const int srow = lane >> 2, scol = (lane & 3) << 3;
        const u16* g = q + (size_t)(b * L + qrow0 + w * 16 + srow) * ldq
                         + qcol0 + h * 32 + scol;
        ASYNC16(&Qs[(w * 16) * 32], g);
    }
    if (SHARED) {   // S=10: scalar staging + zero pad
        for (int idx = t; idx < S16 * 4; idx += 256) {
            const int row = idx >> 2, ch = idx & 3;
            uint4 val = make_uint4(0, 0, 0, 0);
            if (row < S) val = *(const uint4*)&k[(size_t)row * ldk + kcol0 + h * 32 + ch * 8];
            *(uint4*)&Ks[row * 32 + ch * 8] = val;
        }
    } else {
        const int srow = lane >> 2, scol = (lane & 3) << 3;
        for (int c = w; c < S / 16; c += 4) {
            const u16* g = k + (size_t)(b * S + c * 16 + srow) * ldk
                             + kcol0 + h * 32 + scol;
            ASYNC16(&Ks[(c * 16) * 32], g);
        }
    }
    for (int idx = t; idx < 32 * S32 / 8; idx += 256) {
        const int e = idx / (S32 / 8), ch = idx % (S32 / 8);
        const size_t src = SHARED ? ((size_t)(h * 32 + e) * S32 + ch * 8)
                                  : ((((size_t)b * 8 + h) * 32 + e) * S32 + ch * 8);
        *(uint4*)&Vs[e * SP + ch * 8] = *(const uint4*)&VT[src];
    }
    __syncthreads();

    const s8v fq = *(const s8v*)&Qs[(w * 16 + lm) * 32 + kq];
    f4v zac[NT];
    #pragma unroll
    for (int nt = 0; nt < NT; ++nt) {
        const s8v fk = *(const s8v*)&Ks[(nt * 16 + lm) * 32 + kq];
        zac[nt] = MFMA16(fk, fq, f4v{0.f, 0.f, 0.f, 0.f}, 0, 0, 0);
    }
    const float scale = 0.17677669529663687f;  // 1/sqrt(32)
    float z[NT][4];
    #pragma unroll
    for (int nt = 0; nt < NT; ++nt)
        #pragma unroll
        for (int r = 0; r < 4; ++r) {
            float zz = zac[nt][r] * scale;
            if ((S & 15) && nt * 16 + quad * 4 + r >= S) zz = -3.0e38f;
            z[nt][r] = zz;
        }

    float tau = -3.0e38f, kprev = -1.f;
    for (int it = 0; it <= S; ++it) {
        float sum = 0.f;
        int cnt = 0;
        #pragma unroll
        for (int nt = 0; nt < NT; ++nt)
            #pragma unroll
            for (int r = 0; r < 4; ++r) {
                const bool a = z[nt][r] > tau;
                cnt += a;
                sum += a ? z[nt][r] : 0.f;
            }
        sum += __shfl_xor(sum, 16); cnt += __shfl_xor(cnt, 16);
        sum += __shfl_xor(sum, 32); cnt += __shfl_xor(cnt, 32);
        const float fc = (float)cnt;
        const bool anych = (fc != kprev);
        kprev = fc;
        tau = (sum - 1.f) / fc;
        if (__ballot(anych) == 0ULL) break;
    }

    u16* const Prow = &Ps[(w * 16 + lm) * SP];
    #pragma unroll
    for (int nt = 0; nt < NT; ++nt) {
        const u16 p0 = bf16_rne(fmaxf(z[nt][0] - tau, 0.f));
        const u16 p1 = bf16_rne(fmaxf(z[nt][1] - tau, 0.f));
        const u16 p2 = bf16_rne(fmaxf(z[nt][2] - tau, 0.f));
        const u16 p3 = bf16_rne(fmaxf(z[nt][3] - tau, 0.f));
        uint2 hp;
        hp.x = (u32)p0 | ((u32)p1 << 16);
        hp.y = (u32)p2 | ((u32)p3 << 16);
        *(uint2*)&Prow[nt * 16 + quad * 4] = hp;
    }
    if (S16 != S32) {
        uint2 zz; zz.x = 0u; zz.y = 0u;
        *(uint2*)&Prow[S16 + quad * 4] = zz;
    }
    f4v oac[2] = {};
    u16* const Pw = &Ps[(w * 16) * SP];
    #pragma unroll
    for (int kc = 0; kc < KC; ++kc) {
        const s8v fp = *(const s8v*)&Pw[lm * SP + kc * 32 + kq];
        #pragma unroll
        for (int et = 0; et < 2; ++et) {
            const s8v fv = *(const s8v*)&Vs[(et * 16 + lm) * SP + kc * 32 + kq];
            oac[et] = MFMA16(fp, fv, oac[et], 0, 0, 0);
        }
    }
    #pragma unroll
    for (int et = 0; et < 2; ++et)
        #pragma unroll
        for (int r = 0; r < 4; ++r) {
            const int l = qrow0 + w * 16 + quad * 4 + r;
            ho[(((size_t)b * 8 + h) * L + l) * 32 + et * 16 + lm] = bf16_rne(oac[et][r]);
        }
}

// ---- LayerNorm (in-place fp32) + bf16 plane out ----
__global__ __launch_bounds__(256)
void layernorm_dual(float* __restrict__ x, const float* __restrict__ g,
                    const float* __restrict__ bb, u16* __restrict__ oh)
{
    const int w = threadIdx.x >> 6, lane = threadIdx.x & 63;
    const size_t base = ((size_t)blockIdx.x * 4 + w) * 256 + lane * 4;
    const float4 xv = *(const float4*)&x[base];
    float s  = xv.x + xv.y + xv.z + xv.w;
    float sq = xv.x * xv.x + xv.y * xv.y + xv.z * xv.z + xv.w * xv.w;
    #pragma unroll
    for (int off = 32; off >= 1; off >>= 1) {
        s  += __shfl_xor(s, off);
        sq += __shfl_xor(sq, off);
    }
    const float mean = s * (1.f / 256.f);
    const float var  = sq * (1.f / 256.f) - mean * mean;
    const float rstd = rsqrtf(var + 1e-5f);
    const float4 gv = *(const float4*)&g[lane * 4];
    const float4 bv = *(const float4*)&bb[lane * 4];
    float4 o;
    o.x = (xv.x - mean) * rstd * gv.x + bv.x;
    o.y = (xv.y - mean) * rstd * gv.y + bv.y;
    o.z = (xv.z - mean) * rstd * gv.z + bv.z;
    o.w = (xv.w - mean) * rstd * gv.w + bv.w;
    *(float4*)&x[base] = o;
    uint2 hp;
    hp.x = (u32)bf16_rne(o.x) | ((u32)bf16_rne(o.y) << 16);
    hp.y = (u32)bf16_rne(o.z) | ((u32)bf16_rne(o.w) << 16);
    *(uint2*)(oh + base) = hp;
}

extern "C" void kernel_launch(void* const* d_in, const int* in_sizes, int n_in,
                              void* d_out, int out_size, void* d_ws, size_t ws_size,
                              hipStream_t stream)
{
    const float* x      = (const float*)d_in[0];
    const float* ct_wq  = (const float*)d_in[1];  const float* ct_bq = (const float*)d_in[2];
    const float* ct_wk  = (const float*)d_in[3];  const float* ct_bk = (const float*)d_in[4];
    const float* ct_wv  = (const float*)d_in[5];  const float* ct_bv = (const float*)d_in[6];
    const float* ct_wo  = (const float*)d_in[7];  const float* ct_bo = (const float*)d_in[8];
    const float* cs_wq  = (const float*)d_in[9];  const float* cs_bq = (const float*)d_in[10];
    const float* cs_wk  = (const float*)d_in[11]; const float* cs_bk = (const float*)d_in[12];
    const float* cs_wv  = (const float*)d_in[13]; const float* cs_bv = (const float*)d_in[14];
    const float* cs_wo  = (const float*)d_in[15]; const float* cs_bo = (const float*)d_in[16];
    const float* hp_wq  = (const float*)d_in[17]; const float* hp_bq = (const float*)d_in[18];
    const float* hp_wk  = (const float*)d_in[19]; const float* hp_bk = (const float*)d_in[20];
    const float* hp_wv  = (const float*)d_in[21]; const float* hp_bv = (const float*)d_in[22];
    const float* hp_wo  = (const float*)d_in[23]; const float* hp_bo = (const float*)d_in[24];
    const float* cs_key = (const float*)d_in[25];
    const float* ln_g   = (const float*)d_in[26]; const float* ln_b   = (const float*)d_in[27];
    const float* m1_w1  = (const float*)d_in[28]; const float* m1_b1  = (const float*)d_in[29];
    const float* m1_w2  = (const float*)d_in[30]; const float* m1_b2  = (const float*)d_in[31];
    const float* m2_w1  = (const float*)d_in[32]; const float* m2_b1  = (const float*)d_in[33];
    const float* m2_w2  = (const float*)d_in[34]; const float* m2_b2  = (const float*)d_in[35];

    const size_t PS = 8388608ULL;  // u16 per plane (32768 x 256)
    u16* WS = (u16*)d_ws;
    auto SLOT = [&](int i) { return WS + (size_t)i * PS; };
    u16* WT = WS + 8 * PS;
    // weight regions (N,K) bf16:
    u16* Wqk1 = WT;                       // 512*256
    u16* Wv1  = Wqk1 + 512 * 256;         // 256*256
    u16* Wo1  = Wv1  + 65536;
    u16* Wqkq = Wo1  + 65536;             // 768*256
    u16* Wv3  = Wqkq + 768 * 256;
    u16* Wsum = Wv3  + 65536;             // 256 x 512: [cs_wo | hp_wo] K-concat
    u16* Wm11 = Wsum + 131072;            // 1024*256
    u16* Wm12 = Wm11 + 262144;            // 256*1024
    u16* Wm21 = Wm12 + 262144;
    u16* Wm22 = Wm21 + 262144;
    float* bqk1 = (float*)(Wm22 + 262144);      // 512
    float* bqkq = bqk1 + 512;                   // 768
    float* bsum = bqkq + 768;                   // 256 (cs_bo + hp_bo)
    float* kp2f = bsum + 256;                   // 2560
    float* v2f  = kp2f + 2560;                  // 2560
    u16* k2h  = (u16*)(v2f + 2560);             // 2560
    u16* VT2  = k2h + 2560;                     // 8192

    const dim3 blk(256);
    const int M = 32768;

    // ---- batched weight prep (1 launch) + bias concat/sum ----
    {
        WB wb;
        const float* s14[14] = {ct_wq, ct_wk, ct_wv, ct_wo, hp_wq, hp_wk, cs_wq,
                                hp_wv, cs_wo, hp_wo, m1_w1, m1_w2, m2_w1, m2_w2};
        u16* d14[14] = {Wqk1, Wqk1 + 65536, Wv1, Wo1, Wqkq, Wqkq + 65536, Wqkq + 131072,
                        Wv3, Wsum, Wsum + 256, Wm11, Wm12, Wm21, Wm22};
        for (int i = 0; i < 14; ++i) {
            wb.src[i] = s14[i]; wb.dst[i] = d14[i];
            wb.K[i] = (i == 11 || i == 13) ? 1024 : 256;
            wb.N[i] = (i == 10 || i == 12) ? 1024 : 256;
            wb.LD[i] = (i == 8 || i == 9) ? 512 : wb.K[i];
        }
        wconv_batch<<<dim3(256, 14), blk, 0, stream>>>(wb);
        bias_concat<<<dim3(1), blk, 0, stream>>>(ct_bq, ct_bk, bqk1, hp_bq, hp_bk, cs_bq, bqkq,
                                                 cs_bo, hp_bo, bsum);
    }

    // Slot plan (plane lifetimes):
    u16* xh = SLOT(0);
    u16* QK1 = SLOT(1);           // spans S1+S2 (512-wide)
    u16* V1 = SLOT(3);
    u16* VT1 = SLOT(4);
    u16* HO1 = SLOT(0);
    float* DIMINf = (float*)SLOT(5);   // spans S5+S6
    u16* DIMINh = SLOT(4);
    u16* H1 = SLOT(0);            // spans S0..S3
    u16* SER = SLOT(4);           // t8 writes transposed dim_in here (TRS=1)
    u16* QKQ = SLOT(0);           // spans S0,S1,S2 (768-wide)
    u16* V3 = SLOT(3);
    u16* VT3 = SLOT(4);
    u16* HO3 = SLOT(3);
    u16* HO2 = SLOT(7);           // cs attention out (S7 free until DEh->S6)
    float* SUMf = (float*)SLOT(4);     // spans S4+S5
    u16* DEh = SLOT(6);
    u16* H2 = SLOT(0);            // spans S0..S3

    // ---- t1: x -> bf16 plane ----
    conv_hi<<<dim3(4096), blk, 0, stream>>>(x, xh);
    // ---- t2: fused q1|k1 ----
    gemm_bf16<0,0,0,0,0><<<dim3(256, 4), blk, 0, stream>>>(xh, 256, Wqk1, bqk1, nullptr,
                                                       QK1, nullptr, M, 512, 256, nullptr);
    // ---- t3: v1 = V(k1) ----
    gemm_bf16<0,0,0,0,0><<<dim3(256, 2), blk, 0, stream>>>(QK1 + 256, 512, Wv1, ct_bv, nullptr,
                                                       V1, nullptr, M, 256, 256, nullptr);
    // ---- t4: VT1 ----
    transpose_vt<128><<<dim3(2048), blk, 0, stream>>>(V1, VT1);
    // ---- t5: ct attention (S=128, L=128, nb=256) ----
    attn_bf16<128,128,0><<<dim3(4096), blk, 0, stream>>>(QK1, 512, 0, QK1, 512, 256, VT1, HO1);
    // ---- t6: dim_in = x + enc (dual out) ----
    gemm_bf16<0,1,1,0,0><<<dim3(256, 2), blk, 0, stream>>>(HO1, 256, Wo1, ct_bo, x,
                                                       DIMINh, DIMINf, M, 256, 256, nullptr);
    // ---- t7: MLP1 fc1 (gelu) ----
    gemm_bf16<1,0,0,0,0><<<dim3(256, 8), blk, 0, stream>>>(DIMINh, 256, Wm11, m1_b1, nullptr,
                                                       H1, nullptr, M, 1024, 256, nullptr);
    // ---- t8: MLP1 fc2 + residual, transposed out (folds old t9) ----
    gemm_bf16<0,1,0,1,0><<<dim3(256, 2), blk, 0, stream>>>(H1, 1024, Wm12, m1_b2, DIMINf,
                                                       SER, nullptr, M, 256, 1024, nullptr);
    // ---- t10: fused q3|k3|q2 ----
    gemm_bf16<0,0,0,0,0><<<dim3(256, 6), blk, 0, stream>>>(SER, 256, Wqkq, bqkq, nullptr,
                                                       QKQ, nullptr, M, 768, 256, nullptr);
    // ---- t11: v3 = V(k3) ----
    gemm_bf16<0,0,0,0,0><<<dim3(256, 2), blk, 0, stream>>>(QKQ + 256, 768, Wv3, hp_bv, nullptr,
                                                       V3, nullptr, M, 256, 256, nullptr);
    // ---- t12: VT3 ----
    transpose_vt<64><<<dim3(4096), blk, 0, stream>>>(V3, VT3);
    // ---- t13: hp attention (S=64, L=64, nb=512) ----
    attn_bf16<64,64,0><<<dim3(4096), blk, 0, stream>>>(QKQ, 768, 0, QKQ, 768, 256, VT3, HO3);
    // ---- t15: cs tiny chain + attention (S=10 shared) ----
    gemm_tiny<<<dim3(10, 8), blk, 0, stream>>>(cs_key, cs_wk, cs_bk, kp2f, k2h, 256, 256);
    gemm_tiny<<<dim3(10, 8), blk, 0, stream>>>(kp2f, cs_wv, cs_bv, v2f, nullptr, 256, 256);
    cs_vt<<<dim3(1), blk, 0, stream>>>(v2f, VT2);
    attn_bf16<64,10,1><<<dim3(4096), blk, 0, stream>>>(QKQ, 768, 512, k2h, 256, 0, VT2, HO2);
    // ---- t16': sum = HO2@Wo2 + HO3@Wo3 + (cs_bo+hp_bo)  [K=512 fused] ----
    gemm_bf16<0,0,2,0,1><<<dim3(256, 2), blk, 0, stream>>>(HO2, 256, Wsum, bsum, nullptr,
                                                       nullptr, SUMf, M, 256, 512, HO3);
    // ---- t17: LN (in-place) + bf16 plane ----
    layernorm_dual<<<dim3(8192), blk, 0, stream>>>(SUMf, ln_g, ln_b, DEh);
    // ---- t18: MLP2 fc1 (gelu) ----
    gemm_bf16<1,0,0,0,0><<<dim3(256, 8), blk, 0, stream>>>(DEh, 256, Wm21, m2_b1, nullptr,
                                                       H2, nullptr, M, 1024, 256, nullptr);
    // ---- t19: MLP2 fc2 + residual, transposed direct to d_out (folds old t20) ----
    gemm_bf16<0,1,2,2,0><<<dim3(256, 2), blk, 0, stream>>>(H2, 1024, Wm22, m2_b2, SUMf,
                                                       nullptr, (float*)d_out, M, 256, 1024, nullptr);
}

// Round 8
// 535.871 us; speedup vs baseline: 1.0260x; 1.0260x over previous
//
#include <hip/hip_runtime.h>
#include <math.h>

// STHM layer. B=4, TS=64, SEG=128, D=256, H=8, dh=32, DFF=1024.
// Plain-bf16 MFMA GEMMs (BK=64, XOR-swizzled LDS) + single-barrier MFMA attention.
// R3: swapped-QK^T sparsemax. R4: bm-major grid + LDS-staged bf16 C-write.
// R5: t9/t20/t14 fusions. (All CONFIRMED.)
// R7 LESSON: tanh-GELU via exact f32 division REGRESSED (VGPR 80->96, occupancy
//   25->20.6%, FETCH +11MB L2-thrash, fc1 49->76us): div's VCC-serialized
//   fixup sequence costs as much VALU as erff and adds register pressure.
// R8: (a) GELU via v_exp + single v_rcp (__builtin_amdgcn_rcpf) — the VCC-free
//     short form (~5 ops). (b) attention Ps-over-Qs/Ks LDS overlay (+1 barrier):
//     ct 38400->26112B (4->6 blk/CU), hp 22016->13824 (7->8 blk/CU).

typedef unsigned short u16;
typedef unsigned int u32;
typedef __attribute__((ext_vector_type(8))) short s8v;   // 8 bf16 (4 VGPRs) MFMA frag
typedef __attribute__((ext_vector_type(4))) float f4v;   // MFMA accumulator

#define MFMA16 __builtin_amdgcn_mfma_f32_16x16x32_bf16

#define ASYNC16(lds, g) __builtin_amdgcn_global_load_lds( \
    (const __attribute__((address_space(1))) unsigned int*)(const void*)(g), \
    (__attribute__((address_space(3))) unsigned int*)(void*)(lds), 16, 0, 0)

__device__ __forceinline__ float gelu_fast(float x) {
    // tanh-form GELU: x*sigmoid(2u), u = 0.79788456(x+0.044715x^3).
    // exp + single rcp (1ulp) — no VCC-serialized div sequence (R7 lesson).
    const float x2 = x * x;
    const float u2 = x * fmaf(0.0713548162f, x2, 1.5957691216f);   // 2u
    const float e = __expf(-u2);
    return x * __builtin_amdgcn_rcpf(1.0f + e);
}
__device__ __forceinline__ u16 bf16_rne(float f) {
    u32 u = __float_as_uint(f);
    return (u16)((u + 0x7FFFu + ((u >> 16) & 1u)) >> 16);
}
__device__ __forceinline__ float bf16_to_f(u16 h) {
    return __uint_as_float((u32)h << 16);
}

// ---- Batched weight prep: W(K,N fp32) -> Wh (N,K bf16, transposed), 14 mats ----
struct WB {
    const float* src[14];
    u16* dst[14];
    int K[14], N[14], LD[14];
};
__global__ __launch_bounds__(256)
void wconv_batch(WB wb)
{
    __shared__ float tile[32][33];
    const int mi = blockIdx.y;
    const int K = wb.K[mi], N = wb.N[mi], LD = wb.LD[mi];
    const int tilesN = N >> 5;
    if ((int)blockIdx.x >= tilesN * (K >> 5)) return;
    const int n0 = (blockIdx.x % tilesN) * 32, k0 = (blockIdx.x / tilesN) * 32;
    const float* W = wb.src[mi];
    u16* Wh = wb.dst[mi];
    const int t = threadIdx.x;
    const int r = t >> 3, c = (t & 7) << 2;
    const float4 f = *(const float4*)&W[(size_t)(k0 + r) * N + n0 + c];
    tile[r][c] = f.x; tile[r][c + 1] = f.y; tile[r][c + 2] = f.z; tile[r][c + 3] = f.w;
    __syncthreads();
    u32 hp[2];
    #pragma unroll
    for (int p = 0; p < 2; ++p) {
        const u16 h0 = bf16_rne(tile[c + p * 2][r]);
        const u16 h1 = bf16_rne(tile[c + p * 2 + 1][r]);
        hp[p] = (u32)h0 | ((u32)h1 << 16);
    }
    uint2 hv; hv.x = hp[0]; hv.y = hp[1];
    *(uint2*)&Wh[(size_t)(n0 + r) * LD + k0 + c] = hv;
}

// ---- fp32 -> bf16 plane (8 elems/thread) ----
__global__ __launch_bounds__(256)
void conv_hi(const float* __restrict__ x, u16* __restrict__ xh)
{
    const size_t base = ((size_t)blockIdx.x * 256 + threadIdx.x) * 8;
    const float4 a = *(const float4*)(x + base);
    const float4 b = *(const float4*)(x + base + 4);
    const float fs[8] = {a.x, a.y, a.z, a.w, b.x, b.y, b.z, b.w};
    __align__(16) u16 hh[8];
    #pragma unroll
    for (int i = 0; i < 8; ++i) hh[i] = bf16_rne(fs[i]);
    *(uint4*)(xh + base) = *(const uint4*)hh;
}

// ---- bias concat + sum ----
__global__ __launch_bounds__(256)
void bias_concat(const float* a0, const float* a1, float* o1,
                 const float* b0, const float* b1, const float* b2, float* o2,
                 const float* c0, const float* c1, float* o3)
{
    const int t = threadIdx.x;
    o1[t] = a0[t]; o1[256 + t] = a1[t];
    o2[t] = b0[t]; o2[256 + t] = b1[t]; o2[512 + t] = b2[t];
    o3[t] = c0[t] + c1[t];
}

// ---- bf16 MFMA GEMM, BK=64, XOR-swizzled LDS rows (row stride 64 u16) ----
// OUTMODE: 0 bf16 plane, 1 bf16+fp32, 2 fp32 only. TRS: row permutation on out.
// ASPLIT: A for k0<256, A2 for k0>=256.
template<int GELU, int RES, int OUTMODE, int TRS, int ASPLIT>
__global__ __launch_bounds__(256)
void gemm_bf16(const u16* __restrict__ A, int lda, const u16* __restrict__ W,
               const float* __restrict__ bias, const float* __restrict__ Rf,
               u16* __restrict__ Cb, float* __restrict__ Cf,
               int M, int N, int K, const u16* __restrict__ A2)
{
    __shared__ __align__(16) u16 SM[128 * 136];    // As | Ws, re-used as C staging
    u16* const As = SM;
    u16* const Ws = SM + 128 * 64;
    const int t = threadIdx.x;
    const int bm = blockIdx.x, bn = blockIdx.y;
    const int w = t >> 6, lane = t & 63;
    const int wy = w >> 1, wx = w & 1;
    const int lm = lane & 15, quad = lane >> 4, kq = quad << 3;
    const int srow = lane >> 3;                        // 0..7
    const int scol = (((lane & 7) ^ srow) << 3);       // swizzled source chunk (u16)
    const size_t arow = (size_t)(bm * 128 + w * 32 + srow) * lda + scol;
    const u16* gW = W + (size_t)(bn * 128 + w * 32 + srow) * K + scol;
    f4v acc[4][4] = {};   // [ic: out-col tile][jr: act-row tile]
    for (int k0 = 0; k0 < K; k0 += 64) {
        const u16* gAk = (ASPLIT && k0 >= 256) ? (A2 + arow + (k0 - 256))
                                               : (A + arow + k0);
        #pragma unroll
        for (int r8 = 0; r8 < 4; ++r8) {
            ASYNC16(&As[(w * 32 + r8 * 8) * 64], gAk + (size_t)(r8 * 8) * lda);
            ASYNC16(&Ws[(w * 32 + r8 * 8) * 64], gW + k0 + (size_t)(r8 * 8) * K);
        }
        __syncthreads();
        #pragma unroll
        for (int ks = 0; ks < 2; ++ks) {
            const int ch = ks * 4 + quad;              // 16B chunk index 0..7
            const int sw = ((ch ^ (lm & 7)) << 3);     // swizzled read offset (u16)
            s8v fw[4], fa[4];
            #pragma unroll
            for (int i = 0; i < 4; ++i) {
                fw[i] = *(const s8v*)&Ws[(wx * 64 + i * 16 + lm) * 64 + sw];
                fa[i] = *(const s8v*)&As[(wy * 64 + i * 16 + lm) * 64 + sw];
            }
            #pragma unroll
            for (int ic = 0; ic < 4; ++ic)
                #pragma unroll
                for (int jr = 0; jr < 4; ++jr)
                    acc[ic][jr] = MFMA16(fw[ic], fa[jr], acc[ic][jr], 0, 0, 0);
        }
        __syncthreads();
    }
    #pragma unroll
    for (int ic = 0; ic < 4; ++ic) {
        const int cloc = wx * 64 + ic * 16 + (quad << 2);
        const int col0 = bn * 128 + cloc;
        const float4 bv = *(const float4*)&bias[col0];
        #pragma unroll
        for (int jr = 0; jr < 4; ++jr) {
            const int rloc = wy * 64 + jr * 16 + lm;
            const int row = bm * 128 + rloc;
            const size_t o = (size_t)row * N + col0;
            float v[4] = {acc[ic][jr][0] + bv.x, acc[ic][jr][1] + bv.y,
                          acc[ic][jr][2] + bv.z, acc[ic][jr][3] + bv.w};
            if (RES) {
                const float4 rv = *(const float4*)(Rf + o);
                v[0] += rv.x; v[1] += rv.y; v[2] += rv.z; v[3] += rv.w;
            }
            if (GELU) {
                #pragma unroll
                for (int r = 0; r < 4; ++r) v[r] = gelu_fast(v[r]);
            }
            if (OUTMODE != 2) {
                uint2 hp;
                hp.x = (u32)bf16_rne(v[0]) | ((u32)bf16_rne(v[1]) << 16);
                hp.y = (u32)bf16_rne(v[2]) | ((u32)bf16_rne(v[3]) << 16);
                *(uint2*)&SM[rloc * 136 + cloc] = hp;   // stage for coalesced write
            }
            if (OUTMODE >= 1) {
                int prow = row;
                if (TRS == 1) prow = ((row >> 13) << 13) + ((row & 127) << 6) + ((row >> 7) & 63);
                if (TRS == 2) prow = ((row >> 13) << 13) + ((row & 63) << 7) + ((row >> 6) & 127);
                float4 fv; fv.x = v[0]; fv.y = v[1]; fv.z = v[2]; fv.w = v[3];
                *(float4*)(Cf + (size_t)prow * N + col0) = fv;
            }
        }
    }
    if (OUTMODE != 2) {   // coalesced bf16 tile write: full 256B rows (TRS permutes rows)
        __syncthreads();
        #pragma unroll
        for (int p = 0; p < 8; ++p) {
            const int idx = p * 256 + t;
            const int rloc = idx >> 4, ch = (idx & 15) << 3;
            const int row = bm * 128 + rloc;
            int prow = row;
            if (TRS == 1) prow = ((row >> 13) << 13) + ((row & 127) << 6) + ((row >> 7) & 63);
            if (TRS == 2) prow = ((row >> 13) << 13) + ((row & 63) << 7) + ((row >> 6) & 127);
            *(uint4*)&Cb[(size_t)prow * N + bn * 128 + ch] =
                *(const uint4*)&SM[rloc * 136 + ch];
        }
    }
}

// ---- K-parallel tiny GEMM: C(10,N) = A(10,K) @ W(K,N) + bias ----
__global__ __launch_bounds__(256)
void gemm_tiny(const float* __restrict__ A, const float* __restrict__ W,
               const float* __restrict__ bias, float* __restrict__ Cf,
               u16* __restrict__ Ch, int K, int N)
{
    __shared__ float red[8][33];
    const int m = blockIdx.x;
    const int ncol = blockIdx.y * 32 + (threadIdx.x & 31);
    const int ks = threadIdx.x >> 5;
    const int kc = K >> 3;
    float p = 0.f;
    for (int k = ks * kc; k < (ks + 1) * kc; ++k)
        p = fmaf(A[(size_t)m * K + k], W[(size_t)k * N + ncol], p);
    red[ks][threadIdx.x & 31] = p;
    __syncthreads();
    if (ks == 0) {
        float s = bias[ncol];
        #pragma unroll
        for (int i = 0; i < 8; ++i) s += red[i][threadIdx.x & 31];
        Cf[(size_t)m * N + ncol] = s;
        if (Ch) Ch[(size_t)m * N + ncol] = bf16_rne(s);
    }
}

// ---- cs V^T builder: v2f (10,256) fp32 -> VT2 (8,32,32) bf16, j>=10 zero ----
__global__ __launch_bounds__(256)
void cs_vt(const float* __restrict__ v2f, u16* __restrict__ VT2)
{
    const int c = threadIdx.x;   // col = h*32+e
    for (int j = 0; j < 32; ++j)
        VT2[c * 32 + j] = (j < 10) ? bf16_rne(v2f[(size_t)j * 256 + c]) : (u16)0;
}

// ---- V (M,256) bf16 -> VT (nb,8,32,S) bf16; block per (nb_idx, h) ----
template<int S>
__global__ __launch_bounds__(256)
void transpose_vt(const u16* __restrict__ V, u16* __restrict__ VT)
{
    __shared__ __align__(16) u16 Vs[S * 40];
    const int t = threadIdx.x;
    const int nb = blockIdx.x >> 3, h = blockIdx.x & 7;
    for (int idx = t; idx < S * 4; idx += 256) {
        const int row = idx >> 2, ch = idx & 3;
        *(uint4*)&Vs[row * 40 + ch * 8] =
            *(const uint4*)&V[((size_t)nb * S + row) * 256 + h * 32 + ch * 8];
    }
    __syncthreads();
    for (int idx = t; idx < 32 * S / 8; idx += 256) {
        const int e = idx / (S / 8), seg = idx % (S / 8);
        const int j0 = seg * 8;
        __align__(16) u16 tmp[8];
        #pragma unroll
        for (int i = 0; i < 8; ++i) tmp[i] = Vs[(j0 + i) * 40 + e];
        *(uint4*)&VT[(((size_t)nb * 8 + h) * 32 + e) * S + j0] = *(const uint4*)tmp;
    }
}

// ---- bf16 MFMA attention: swapped QK^T -> Michelot sparsemax -> P@V^T ----
// Ps overlays Qs|Ks (dead after QK^T fragments are in regs); 2nd barrier
// separates the last Q/K read from the first P write. LDS: ct 26112B (6 blk/CU),
// hp 13824B (8 blk/CU), cs 7680B.
template<int L, int S, int SHARED>
__global__ __launch_bounds__(256)
void attn_bf16(const u16* __restrict__ q, int ldq, int qcol0,
               const u16* __restrict__ k, int ldk, int kcol0,
               const u16* __restrict__ VT, u16* __restrict__ ho)
{
    constexpr int S16 = (S + 15) & ~15;
    constexpr int S32 = (S + 31) & ~31;
    constexpr int NT = S16 / 16;
    constexpr int KC = S32 / 32;
    constexpr int LC = L / 64;
    constexpr int SP = S32 + 8;
    constexpr int QK_B = 64 * 32 * 2 + S16 * 32 * 2;   // Qs + Ks bytes
    constexpr int PS_B = 64 * SP * 2;                  // Ps bytes
    constexpr int R0 = (QK_B > PS_B) ? QK_B : PS_B;    // overlaid region
    __shared__ __align__(16) unsigned char SMEM[R0 + 32 * SP * 2];
    u16* const Qs = (u16*)SMEM;
    u16* const Ks = (u16*)(SMEM + 64 * 32 * 2);
    u16* const Ps = (u16*)SMEM;                        // overlays Qs|Ks after barrier 2
    u16* const Vs = (u16*)(SMEM + R0);
    const int t = threadIdx.x;
    const int lc = (LC == 1) ? 0 : (blockIdx.x & (LC - 1));
    const int bh = (LC == 1) ? blockIdx.x : (blockIdx.x >> 1);
    const int b = bh >> 3, h = bh & 7;
    const int qrow0 = lc * 64;
    const int w = t >> 6, lane = t & 63;
    const int lm = lane & 15, quad = lane >> 4, kq = quad << 3;

    {
        const int srow = lane >> 2, scol = (lane & 3) << 3;
        const u16* g = q + (size_t)(b * L + qrow0 + w * 16 + srow) * ldq
                         + qcol0 + h * 32 + scol;
        ASYNC16(&Qs[(w * 16) * 32], g);
    }
    if (SHARED) {   // S=10: scalar staging + zero pad
        for (int idx = t; idx < S16 * 4; idx += 256) {
            const int row = idx >> 2, ch = idx & 3;
            uint4 val = make_uint4(0, 0, 0, 0);
            if (row < S) val = *(const uint4*)&k[(size_t)row * ldk + kcol0 + h * 32 + ch * 8];
            *(uint4*)&Ks[row * 32 + ch * 8] = val;
        }
    } else {
        const int srow = lane >> 2, scol = (lane & 3) << 3;
        for (int c = w; c < S / 16; c += 4) {
            const u16* g = k + (size_t)(b * S + c * 16 + srow) * ldk
                             + kcol0 + h * 32 + scol;
            ASYNC16(&Ks[(c * 16) * 32], g);
        }
    }
    for (int idx = t; idx < 32 * S32 / 8; idx += 256) {
        const int e = idx / (S32 / 8), ch = idx % (S32 / 8);
        const size_t src = SHARED ? ((size_t)(h * 32 + e) * S32 + ch * 8)
                                  : ((((size_t)b * 8 + h) * 32 + e) * S32 + ch * 8);
        *(uint4*)&Vs[e * SP + ch * 8] = *(const uint4*)&VT[src];
    }
    __syncthreads();

    // --- QK^T swapped: D[m=s][n=q]; lane lm = q-row, regs walk s ---
    const s8v fq = *(const s8v*)&Qs[(w * 16 + lm) * 32 + kq];
    f4v zac[NT];
    #pragma unroll
    for (int nt = 0; nt < NT; ++nt) {
        const s8v fk = *(const s8v*)&Ks[(nt * 16 + lm) * 32 + kq];
        zac[nt] = MFMA16(fk, fq, f4v{0.f, 0.f, 0.f, 0.f}, 0, 0, 0);
    }
    const float scale = 0.17677669529663687f;  // 1/sqrt(32)
    float z[NT][4];
    #pragma unroll
    for (int nt = 0; nt < NT; ++nt)
        #pragma unroll
        for (int r = 0; r < 4; ++r) {
            float zz = zac[nt][r] * scale;
            if ((S & 15) && nt * 16 + quad * 4 + r >= S) zz = -3.0e38f;
            z[nt][r] = zz;
        }
    __syncthreads();   // all waves done reading Qs/Ks; Ps may overwrite

    float tau = -3.0e38f, kprev = -1.f;
    for (int it = 0; it <= S; ++it) {
        float sum = 0.f;
        int cnt = 0;
        #pragma unroll
        for (int nt = 0; nt < NT; ++nt)
            #pragma unroll
            for (int r = 0; r < 4; ++r) {
                const bool a = z[nt][r] > tau;
                cnt += a;
                sum += a ? z[nt][r] : 0.f;
            }
        sum += __shfl_xor(sum, 16); cnt += __shfl_xor(cnt, 16);
        sum += __shfl_xor(sum, 32); cnt += __shfl_xor(cnt, 32);
        const float fc = (float)cnt;
        const bool anych = (fc != kprev);
        kprev = fc;
        tau = (sum - 1.f) / fc;
        if (__ballot(anych) == 0ULL) break;
    }

    u16* const Prow = &Ps[(w * 16 + lm) * SP];
    #pragma unroll
    for (int nt = 0; nt < NT; ++nt) {
        const u16 p0 = bf16_rne(fmaxf(z[nt][0] - tau, 0.f));
        const u16 p1 = bf16_rne(fmaxf(z[nt][1] - tau, 0.f));
        const u16 p2 = bf16_rne(fmaxf(z[nt][2] - tau, 0.f));
        const u16 p3 = bf16_rne(fmaxf(z[nt][3] - tau, 0.f));
        uint2 hp;
        hp.x = (u32)p0 | ((u32)p1 << 16);
        hp.y = (u32)p2 | ((u32)p3 << 16);
        *(uint2*)&Prow[nt * 16 + quad * 4] = hp;
    }
    if (S16 != S32) {
        uint2 zz; zz.x = 0u; zz.y = 0u;
        *(uint2*)&Prow[S16 + quad * 4] = zz;
    }
    f4v oac[2] = {};
    u16* const Pw = &Ps[(w * 16) * SP];
    #pragma unroll
    for (int kc = 0; kc < KC; ++kc) {
        const s8v fp = *(const s8v*)&Pw[lm * SP + kc * 32 + kq];
        #pragma unroll
        for (int et = 0; et < 2; ++et) {
            const s8v fv = *(const s8v*)&Vs[(et * 16 + lm) * SP + kc * 32 + kq];
            oac[et] = MFMA16(fp, fv, oac[et], 0, 0, 0);
        }
    }
    #pragma unroll
    for (int et = 0; et < 2; ++et)
        #pragma unroll
        for (int r = 0; r < 4; ++r) {
            const int l = qrow0 + w * 16 + quad * 4 + r;
            ho[(((size_t)b * 8 + h) * L + l) * 32 + et * 16 + lm] = bf16_rne(oac[et][r]);
        }
}

// ---- LayerNorm (in-place fp32) + bf16 plane out ----
__global__ __launch_bounds__(256)
void layernorm_dual(float* __restrict__ x, const float* __restrict__ g,
                    const float* __restrict__ bb, u16* __restrict__ oh)
{
    const int w = threadIdx.x >> 6, lane = threadIdx.x & 63;
    const size_t base = ((size_t)blockIdx.x * 4 + w) * 256 + lane * 4;
    const float4 xv = *(const float4*)&x[base];
    float s  = xv.x + xv.y + xv.z + xv.w;
    float sq = xv.x * xv.x + xv.y * xv.y + xv.z * xv.z + xv.w * xv.w;
    #pragma unroll
    for (int off = 32; off >= 1; off >>= 1) {
        s  += __shfl_xor(s, off);
        sq += __shfl_xor(sq, off);
    }
    const float mean = s * (1.f / 256.f);
    const float var  = sq * (1.f / 256.f) - mean * mean;
    const float rstd = rsqrtf(var + 1e-5f);
    const float4 gv = *(const float4*)&g[lane * 4];
    const float4 bv = *(const float4*)&bb[lane * 4];
    float4 o;
    o.x = (xv.x - mean) * rstd * gv.x + bv.x;
    o.y = (xv.y - mean) * rstd * gv.y + bv.y;
    o.z = (xv.z - mean) * rstd * gv.z + bv.z;
    o.w = (xv.w - mean) * rstd * gv.w + bv.w;
    *(float4*)&x[base] = o;
    uint2 hp;
    hp.x = (u32)bf16_rne(o.x) | ((u32)bf16_rne(o.y) << 16);
    hp.y = (u32)bf16_rne(o.z) | ((u32)bf16_rne(o.w) << 16);
    *(uint2*)(oh + base) = hp;
}

extern "C" void kernel_launch(void* const* d_in, const int* in_sizes, int n_in,
                              void* d_out, int out_size, void* d_ws, size_t ws_size,
                              hipStream_t stream)
{
    const float* x      = (const float*)d_in[0];
    const float* ct_wq  = (const float*)d_in[1];  const float* ct_bq = (const float*)d_in[2];
    const float* ct_wk  = (const float*)d_in[3];  const float* ct_bk = (const float*)d_in[4];
    const float* ct_wv  = (const float*)d_in[5];  const float* ct_bv = (const float*)d_in[6];
    const float* ct_wo  = (const float*)d_in[7];  const float* ct_bo = (const float*)d_in[8];
    const float* cs_wq  = (const float*)d_in[9];  const float* cs_bq = (const float*)d_in[10];
    const float* cs_wk  = (const float*)d_in[11]; const float* cs_bk = (const float*)d_in[12];
    const float* cs_wv  = (const float*)d_in[13]; const float* cs_bv = (const float*)d_in[14];
    const float* cs_wo  = (const float*)d_in[15]; const float* cs_bo = (const float*)d_in[16];
    const float* hp_wq  = (const float*)d_in[17]; const float* hp_bq = (const float*)d_in[18];
    const float* hp_wk  = (const float*)d_in[19]; const float* hp_bk = (const float*)d_in[20];
    const float* hp_wv  = (const float*)d_in[21]; const float* hp_bv = (const float*)d_in[22];
    const float* hp_wo  = (const float*)d_in[23]; const float* hp_bo = (const float*)d_in[24];
    const float* cs_key = (const float*)d_in[25];
    const float* ln_g   = (const float*)d_in[26]; const float* ln_b   = (const float*)d_in[27];
    const float* m1_w1  = (const float*)d_in[28]; const float* m1_b1  = (const float*)d_in[29];
    const float* m1_w2  = (const float*)d_in[30]; const float* m1_b2  = (const float*)d_in[31];
    const float* m2_w1  = (const float*)d_in[32]; const float* m2_b1  = (const float*)d_in[33];
    const float* m2_w2  = (const float*)d_in[34]; const float* m2_b2  = (const float*)d_in[35];

    const size_t PS = 8388608ULL;  // u16 per plane (32768 x 256)
    u16* WS = (u16*)d_ws;
    auto SLOT = [&](int i) { return WS + (size_t)i * PS; };
    u16* WT = WS + 8 * PS;
    // weight regions (N,K) bf16:
    u16* Wqk1 = WT;                       // 512*256
    u16* Wv1  = Wqk1 + 512 * 256;         // 256*256
    u16* Wo1  = Wv1  + 65536;
    u16* Wqkq = Wo1  + 65536;             // 768*256
    u16* Wv3  = Wqkq + 768 * 256;
    u16* Wsum = Wv3  + 65536;             // 256 x 512: [cs_wo | hp_wo] K-concat
    u16* Wm11 = Wsum + 131072;            // 1024*256
    u16* Wm12 = Wm11 + 262144;            // 256*1024
    u16* Wm21 = Wm12 + 262144;
    u16* Wm22 = Wm21 + 262144;
    float* bqk1 = (float*)(Wm22 + 262144);      // 512
    float* bqkq = bqk1 + 512;                   // 768
    float* bsum = bqkq + 768;                   // 256 (cs_bo + hp_bo)
    float* kp2f = bsum + 256;                   // 2560
    float* v2f  = kp2f + 2560;                  // 2560
    u16* k2h  = (u16*)(v2f + 2560);             // 2560
    u16* VT2  = k2h + 2560;                     // 8192

    const dim3 blk(256);
    const int M = 32768;

    // ---- batched weight prep (1 launch) + bias concat/sum ----
    {
        WB wb;
        const float* s14[14] = {ct_wq, ct_wk, ct_wv, ct_wo, hp_wq, hp_wk, cs_wq,
                                hp_wv, cs_wo, hp_wo, m1_w1, m1_w2, m2_w1, m2_w2};
        u16* d14[14] = {Wqk1, Wqk1 + 65536, Wv1, Wo1, Wqkq, Wqkq + 65536, Wqkq + 131072,
                        Wv3, Wsum, Wsum + 256, Wm11, Wm12, Wm21, Wm22};
        for (int i = 0; i < 14; ++i) {
            wb.src[i] = s14[i]; wb.dst[i] = d14[i];
            wb.K[i] = (i == 11 || i == 13) ? 1024 : 256;
            wb.N[i] = (i == 10 || i == 12) ? 1024 : 256;
            wb.LD[i] = (i == 8 || i == 9) ? 512 : wb.K[i];
        }
        wconv_batch<<<dim3(256, 14), blk, 0, stream>>>(wb);
        bias_concat<<<dim3(1), blk, 0, stream>>>(ct_bq, ct_bk, bqk1, hp_bq, hp_bk, cs_bq, bqkq,
                                                 cs_bo, hp_bo, bsum);
    }

    // Slot plan (plane lifetimes):
    u16* xh = SLOT(0);
    u16* QK1 = SLOT(1);           // spans S1+S2 (512-wide)
    u16* V1 = SLOT(3);
    u16* VT1 = SLOT(4);
    u16* HO1 = SLOT(0);
    float* DIMINf = (float*)SLOT(5);   // spans S5+S6
    u16* DIMINh = SLOT(4);
    u16* H1 = SLOT(0);            // spans S0..S3
    u16* SER = SLOT(4);           // t8 writes transposed dim_in here (TRS=1)
    u16* QKQ = SLOT(0);           // spans S0,S1,S2 (768-wide)
    u16* V3 = SLOT(3);
    u16* VT3 = SLOT(4);
    u16* HO3 = SLOT(3);
    u16* HO2 = SLOT(7);           // cs attention out (S7 free until DEh->S6)
    float* SUMf = (float*)SLOT(4);     // spans S4+S5
    u16* DEh = SLOT(6);
    u16* H2 = SLOT(0);            // spans S0..S3

    // ---- t1: x -> bf16 plane ----
    conv_hi<<<dim3(4096), blk, 0, stream>>>(x, xh);
    // ---- t2: fused q1|k1 ----
    gemm_bf16<0,0,0,0,0><<<dim3(256, 4), blk, 0, stream>>>(xh, 256, Wqk1, bqk1, nullptr,
                                                       QK1, nullptr, M, 512, 256, nullptr);
    // ---- t3: v1 = V(k1) ----
    gemm_bf16<0,0,0,0,0><<<dim3(256, 2), blk, 0, stream>>>(QK1 + 256, 512, Wv1, ct_bv, nullptr,
                                                       V1, nullptr, M, 256, 256, nullptr);
    // ---- t4: VT1 ----
    transpose_vt<128><<<dim3(2048), blk, 0, stream>>>(V1, VT1);
    // ---- t5: ct attention (S=128, L=128, nb=256) ----
    attn_bf16<128,128,0><<<dim3(4096), blk, 0, stream>>>(QK1, 512, 0, QK1, 512, 256, VT1, HO1);
    // ---- t6: dim_in = x + enc (dual out) ----
    gemm_bf16<0,1,1,0,0><<<dim3(256, 2), blk, 0, stream>>>(HO1, 256, Wo1, ct_bo, x,
                                                       DIMINh, DIMINf, M, 256, 256, nullptr);
    // ---- t7: MLP1 fc1 (gelu) ----
    gemm_bf16<1,0,0,0,0><<<dim3(256, 8), blk, 0, stream>>>(DIMINh, 256, Wm11, m1_b1, nullptr,
                                                       H1, nullptr, M, 1024, 256, nullptr);
    // ---- t8: MLP1 fc2 + residual, transposed out (folds old t9) ----
    gemm_bf16<0,1,0,1,0><<<dim3(256, 2), blk, 0, stream>>>(H1, 1024, Wm12, m1_b2, DIMINf,
                                                       SER, nullptr, M, 256, 1024, nullptr);
    // ---- t10: fused q3|k3|q2 ----
    gemm_bf16<0,0,0,0,0><<<dim3(256, 6), blk, 0, stream>>>(SER, 256, Wqkq, bqkq, nullptr,
                                                       QKQ, nullptr, M, 768, 256, nullptr);
    // ---- t11: v3 = V(k3) ----
    gemm_bf16<0,0,0,0,0><<<dim3(256, 2), blk, 0, stream>>>(QKQ + 256, 768, Wv3, hp_bv, nullptr,
                                                       V3, nullptr, M, 256, 256, nullptr);
    // ---- t12: VT3 ----
    transpose_vt<64><<<dim3(4096), blk, 0, stream>>>(V3, VT3);
    // ---- t13: hp attention (S=64, L=64, nb=512) ----
    attn_bf16<64,64,0><<<dim3(4096), blk, 0, stream>>>(QKQ, 768, 0, QKQ, 768, 256, VT3, HO3);
    // ---- t15: cs tiny chain + attention (S=10 shared) ----
    gemm_tiny<<<dim3(10, 8), blk, 0, stream>>>(cs_key, cs_wk, cs_bk, kp2f, k2h, 256, 256);
    gemm_tiny<<<dim3(10, 8), blk, 0, stream>>>(kp2f, cs_wv, cs_bv, v2f, nullptr, 256, 256);
    cs_vt<<<dim3(1), blk, 0, stream>>>(v2f, VT2);
    attn_bf16<64,10,1><<<dim3(4096), blk, 0, stream>>>(QKQ, 768, 512, k2h, 256, 0, VT2, HO2);
    // ---- t16': sum = HO2@Wo2 + HO3@Wo3 + (cs_bo+hp_bo)  [K=512 fused] ----
    gemm_bf16<0,0,2,0,1><<<dim3(256, 2), blk, 0, stream>>>(HO2, 256, Wsum, bsum, nullptr,
                                                       nullptr, SUMf, M, 256, 512, HO3);
    // ---- t17: LN (in-place) + bf16 plane ----
    layernorm_dual<<<dim3(8192), blk, 0, stream>>>(SUMf, ln_g, ln_b, DEh);
    // ---- t18: MLP2 fc1 (gelu) ----
    gemm_bf16<1,0,0,0,0><<<dim3(256, 8), blk, 0, stream>>>(DEh, 256, Wm21, m2_b1, nullptr,
                                                       H2, nullptr, M, 1024, 256, nullptr);
    // ---- t19: MLP2 fc2 + residual, transposed direct to d_out (folds old t20) ----
    gemm_bf16<0,1,2,2,0><<<dim3(256, 2), blk, 0, stream>>>(H2, 1024, Wm22, m2_b2, SUMf,
                                                       nullptr, (float*)d_out, M, 256, 1024, nullptr);
}